// Round 1
// baseline (819.443 us; speedup 1.0000x reference)
//
#include <hip/hip_runtime.h>
#include <math.h>

#define N_NODES 50000
#define EDGES   1600000
#define IN_F    256
#define AD      128
#define H       8
#define DK      16

// ---------------- zero init for the segment-sum table ----------------
__global__ void zero_kernel(float* __restrict__ p, int n) {
    int i = blockIdx.x * blockDim.x + threadIdx.x;
    if (i < n) p[i] = 0.0f;
}

// ---------------- node projections: q = hi@Qw.T + Qb, k = hi@Kw.T + Kb ----
// Block tile: 32 nodes x (128 q-cols + 128 k-cols). 256 threads:
//   half = t>>7 selects Q or K; cg = (t&127)&31 -> 4 cols; ng = (t&127)>>5 -> 8 nodes.
// hi tile staged in LDS (32 KB); W rows read through L1/L2 (256 KB/block, cached).
__global__ __launch_bounds__(256) void proj_kernel(
    const float* __restrict__ hi,
    const float* __restrict__ Qw, const float* __restrict__ Qb,
    const float* __restrict__ Kw, const float* __restrict__ Kb,
    float* __restrict__ q, float* __restrict__ k)
{
    __shared__ float lds[32 * IN_F];            // 32 KB
    const int node0 = blockIdx.x * 32;

    // cooperative load of hi tile: 32 rows x 64 float4
    const float4* hi4 = (const float4*)hi;
    float4* lds4 = (float4*)lds;
    for (int idx = threadIdx.x; idx < 32 * 64; idx += 256) {
        int row = idx >> 6;
        float4 v = make_float4(0.f, 0.f, 0.f, 0.f);
        if (node0 + row < N_NODES) v = hi4[(size_t)node0 * 64 + idx];
        lds4[idx] = v;
    }
    __syncthreads();

    const int t    = threadIdx.x;
    const int half = t >> 7;        // 0 = Q, 1 = K
    const int th   = t & 127;
    const int cg   = th & 31;       // column group: cols 4*cg .. 4*cg+3
    const int ng   = th >> 5;       // node group: nodes 8*ng .. 8*ng+7

    const float4* W4 = (const float4*)(half ? Kw : Qw);

    float acc[8][4];
#pragma unroll
    for (int n = 0; n < 8; n++)
#pragma unroll
        for (int c = 0; c < 4; c++) acc[n][c] = 0.f;

    for (int kd4 = 0; kd4 < IN_F / 4; kd4++) {
        float4 w0 = W4[(size_t)(4 * cg + 0) * 64 + kd4];
        float4 w1 = W4[(size_t)(4 * cg + 1) * 64 + kd4];
        float4 w2 = W4[(size_t)(4 * cg + 2) * 64 + kd4];
        float4 w3 = W4[(size_t)(4 * cg + 3) * 64 + kd4];
#pragma unroll
        for (int n = 0; n < 8; n++) {
            float4 h = lds4[(size_t)(8 * ng + n) * 64 + kd4]; // wave-broadcast read
            acc[n][0] += h.x * w0.x + h.y * w0.y + h.z * w0.z + h.w * w0.w;
            acc[n][1] += h.x * w1.x + h.y * w1.y + h.z * w1.z + h.w * w1.w;
            acc[n][2] += h.x * w2.x + h.y * w2.y + h.z * w2.z + h.w * w2.w;
            acc[n][3] += h.x * w3.x + h.y * w3.y + h.z * w3.z + h.w * w3.w;
        }
    }

    const float4 bias = ((const float4*)(half ? Kb : Qb))[cg];
    float* out = half ? k : q;
#pragma unroll
    for (int n = 0; n < 8; n++) {
        int node = node0 + 8 * ng + n;
        if (node < N_NODES) {
            float4 o;
            o.x = acc[n][0] + bias.x;
            o.y = acc[n][1] + bias.y;
            o.z = acc[n][2] + bias.z;
            o.w = acc[n][3] + bias.w;
            ((float4*)out)[(size_t)node * 32 + cg] = o;
        }
    }
}

// ---------------- edge pass: one wave per edge -------------------------
// prods[e,h] = (q[e0,h].k[e1,h] + radial[e]*(Qrw_h.k[e1,h]) + Qrb_h.k[e1,h])/4
// All three dots reduced together via shfl_xor over 8-lane (=one head) groups.
// Also writes ex=exp(p) into the attention slot and atomically accumulates
// the segment sum (softmax without max-subtraction: |p| <~ 5, safe in fp32).
__global__ __launch_bounds__(256) void edge_kernel(
    const float* __restrict__ q, const float* __restrict__ k,
    const float* __restrict__ radial, const int* __restrict__ edge,
    const float* __restrict__ Qrw, const float* __restrict__ Qrb,
    float* __restrict__ att, float* __restrict__ prods, float* __restrict__ ssum)
{
    const int wave = (blockIdx.x * blockDim.x + threadIdx.x) >> 6;
    const int lane = threadIdx.x & 63;
    if (wave >= EDGES) return;
    const int e  = wave;
    const int e0 = edge[e];
    const int e1 = edge[EDGES + e];

    const float2 qv = ((const float2*)(q + (size_t)e0 * AD))[lane];
    const float2 kv = ((const float2*)(k + (size_t)e1 * AD))[lane];
    const float2 rw = ((const float2*)Qrw)[lane];
    const float2 rb = ((const float2*)Qrb)[lane];

    float a = qv.x * kv.x + qv.y * kv.y;
    float b = rw.x * kv.x + rw.y * kv.y;
    float c = rb.x * kv.x + rb.y * kv.y;
#pragma unroll
    for (int m = 1; m < 8; m <<= 1) {
        a += __shfl_xor(a, m, 64);
        b += __shfl_xor(b, m, 64);
        c += __shfl_xor(c, m, 64);
    }
    if ((lane & 7) == 0) {
        const int h = lane >> 3;
        const float r = radial[e];
        const float p = (a + r * b + c) * 0.25f;   // 1/sqrt(DK)=0.25
        prods[(size_t)e * H + h] = p;
        const float ex = __expf(p);
        att[(size_t)e * H + h] = ex;
        atomicAdd(&ssum[(size_t)e0 * H + h], ex);
    }
}

// ---------------- normalize: attention = ex / s[e0,h] ------------------
__global__ __launch_bounds__(256) void norm_kernel(
    float* __restrict__ att, const float* __restrict__ ssum,
    const int* __restrict__ edge)
{
    const int i = blockIdx.x * blockDim.x + threadIdx.x;
    if (i < EDGES * H) {
        const int e  = i >> 3;
        const int h  = i & 7;
        const int e0 = edge[e];
        att[i] = att[i] / ssum[(size_t)e0 * H + h];
    }
}

extern "C" void kernel_launch(void* const* d_in, const int* in_sizes, int n_in,
                              void* d_out, int out_size, void* d_ws, size_t ws_size,
                              hipStream_t stream) {
    const float* hi     = (const float*)d_in[0];
    const float* radial = (const float*)d_in[1];
    const float* Qw     = (const float*)d_in[2];
    const float* Qb     = (const float*)d_in[3];
    const float* Qrw    = (const float*)d_in[4];
    const float* Qrb    = (const float*)d_in[5];
    const float* Kw     = (const float*)d_in[6];
    const float* Kb     = (const float*)d_in[7];
    const int*   edge   = (const int*)d_in[8];

    float* att   = (float*)d_out;                    // [E, H]
    float* prods = att + (size_t)EDGES * H;          // [E, H]

    float* q    = (float*)d_ws;                      // N*AD
    float* k    = q + (size_t)N_NODES * AD;          // N*AD
    float* ssum = k + (size_t)N_NODES * AD;          // N*H

    zero_kernel<<<(N_NODES * H + 255) / 256, 256, 0, stream>>>(ssum, N_NODES * H);
    proj_kernel<<<(N_NODES + 31) / 32, 256, 0, stream>>>(hi, Qw, Qb, Kw, Kb, q, k);
    edge_kernel<<<(EDGES + 3) / 4, 256, 0, stream>>>(q, k, radial, edge, Qrw, Qrb,
                                                     att, prods, ssum);
    norm_kernel<<<(EDGES * H + 255) / 256, 256, 0, stream>>>(att, ssum, edge);
}

// Round 2
// 528.311 us; speedup vs baseline: 1.5511x; 1.5511x over previous
//
#include <hip/hip_runtime.h>
#include <hip/hip_fp16.h>
#include <math.h>

#define N_NODES 50000
#define EDGES   1600000
#define IN_F    256
#define AD      128
#define H       8
#define DK      16

typedef __attribute__((ext_vector_type(8))) _Float16 half8;

// ---------------- zero init for the segment-sum table ----------------
__global__ void zero_kernel(float* __restrict__ p, int n) {
    int i = blockIdx.x * blockDim.x + threadIdx.x;
    if (i < n) p[i] = 0.0f;
}

// ---------------- node projections: q = hi@Qw.T + Qb, k = hi@Kw.T + Kb ----
// Same tiling as R0; epilogue now emits fp16 q/k (halves edge-gather traffic).
__global__ __launch_bounds__(256) void proj_kernel(
    const float* __restrict__ hi,
    const float* __restrict__ Qw, const float* __restrict__ Qb,
    const float* __restrict__ Kw, const float* __restrict__ Kb,
    __half* __restrict__ qh, __half* __restrict__ kh)
{
    __shared__ float lds[32 * IN_F];            // 32 KB
    const int node0 = blockIdx.x * 32;

    const float4* hi4 = (const float4*)hi;
    float4* lds4 = (float4*)lds;
    for (int idx = threadIdx.x; idx < 32 * 64; idx += 256) {
        int row = idx >> 6;
        float4 v = make_float4(0.f, 0.f, 0.f, 0.f);
        if (node0 + row < N_NODES) v = hi4[(size_t)node0 * 64 + idx];
        lds4[idx] = v;
    }
    __syncthreads();

    const int t    = threadIdx.x;
    const int sel  = t >> 7;        // 0 = Q, 1 = K
    const int th   = t & 127;
    const int cg   = th & 31;       // column group: cols 4*cg .. 4*cg+3
    const int ng   = th >> 5;       // node group: nodes 8*ng .. 8*ng+7

    const float4* W4 = (const float4*)(sel ? Kw : Qw);

    float acc[8][4];
#pragma unroll
    for (int n = 0; n < 8; n++)
#pragma unroll
        for (int c = 0; c < 4; c++) acc[n][c] = 0.f;

    for (int kd4 = 0; kd4 < IN_F / 4; kd4++) {
        float4 w0 = W4[(size_t)(4 * cg + 0) * 64 + kd4];
        float4 w1 = W4[(size_t)(4 * cg + 1) * 64 + kd4];
        float4 w2 = W4[(size_t)(4 * cg + 2) * 64 + kd4];
        float4 w3 = W4[(size_t)(4 * cg + 3) * 64 + kd4];
#pragma unroll
        for (int n = 0; n < 8; n++) {
            float4 h = lds4[(size_t)(8 * ng + n) * 64 + kd4];
            acc[n][0] += h.x * w0.x + h.y * w0.y + h.z * w0.z + h.w * w0.w;
            acc[n][1] += h.x * w1.x + h.y * w1.y + h.z * w1.z + h.w * w1.w;
            acc[n][2] += h.x * w2.x + h.y * w2.y + h.z * w2.z + h.w * w2.w;
            acc[n][3] += h.x * w3.x + h.y * w3.y + h.z * w3.z + h.w * w3.w;
        }
    }

    const float4 bias = ((const float4*)(sel ? Kb : Qb))[cg];
    __half* out = sel ? kh : qh;
#pragma unroll
    for (int n = 0; n < 8; n++) {
        int node = node0 + 8 * ng + n;
        if (node < N_NODES) {
            __half2 p01 = __floats2half2_rn(acc[n][0] + bias.x, acc[n][1] + bias.y);
            __half2 p23 = __floats2half2_rn(acc[n][2] + bias.z, acc[n][3] + bias.w);
            __half2* dst = (__half2*)(out + (size_t)node * AD + 4 * cg);
            dst[0] = p01;
            dst[1] = p23;
        }
    }
}

// ---------------- edge pass: one THREAD per (edge, head) ----------------
// tid = e*8 + h. Each lane loads its own 16 fp16 q + 16 fp16 k values
// (2x dwordx4 each; 8 lanes of one edge cover 256 B contiguous per row),
// computes the three dots locally (no cross-lane reduction), writes
// prods/att coalesced, and atomically accumulates the segment sum.
__global__ __launch_bounds__(256) void edge_kernel(
    const __half* __restrict__ qh, const __half* __restrict__ kh,
    const float* __restrict__ radial, const int* __restrict__ edge,
    const float* __restrict__ Qrw, const float* __restrict__ Qrb,
    float* __restrict__ att, float* __restrict__ prods, float* __restrict__ ssum)
{
    const int t = blockIdx.x * blockDim.x + threadIdx.x;
    const int e = t >> 3;
    const int h = t & 7;
    if (e >= EDGES) return;

    const int e0 = edge[e];
    const int e1 = edge[EDGES + e];

    const half8* qp = (const half8*)(qh + (size_t)e0 * AD + h * DK);
    const half8* kp = (const half8*)(kh + (size_t)e1 * AD + h * DK);
    half8 q0 = qp[0], q1 = qp[1];
    half8 k0 = kp[0], k1 = kp[1];

    const float4* rw4 = (const float4*)(Qrw + h * DK);
    const float4* rb4 = (const float4*)(Qrb + h * DK);
    float rw[16], rb[16];
#pragma unroll
    for (int j = 0; j < 4; j++) {
        float4 w = rw4[j];
        rw[4 * j + 0] = w.x; rw[4 * j + 1] = w.y; rw[4 * j + 2] = w.z; rw[4 * j + 3] = w.w;
        float4 b = rb4[j];
        rb[4 * j + 0] = b.x; rb[4 * j + 1] = b.y; rb[4 * j + 2] = b.z; rb[4 * j + 3] = b.w;
    }

    float a = 0.f, b = 0.f, c = 0.f;
#pragma unroll
    for (int i = 0; i < 8; i++) {
        float qf = (float)q0[i], kf = (float)k0[i];
        a += qf * kf;
        b += rw[i] * kf;
        c += rb[i] * kf;
    }
#pragma unroll
    for (int i = 0; i < 8; i++) {
        float qf = (float)q1[i], kf = (float)k1[i];
        a += qf * kf;
        b += rw[8 + i] * kf;
        c += rb[8 + i] * kf;
    }

    const float r = radial[e];
    const float p = (a + r * b + c) * 0.25f;   // 1/sqrt(DK) = 0.25
    prods[t] = p;                               // t == e*H + h
    const float ex = __expf(p);
    att[t] = ex;
    atomicAdd(&ssum[e0 * H + h], ex);
}

// ---------------- normalize: attention = ex / s[e0,h] ------------------
__global__ __launch_bounds__(256) void norm_kernel(
    float* __restrict__ att, const float* __restrict__ ssum,
    const int* __restrict__ edge)
{
    const int i = blockIdx.x * blockDim.x + threadIdx.x;
    if (i < EDGES * H) {
        const int e  = i >> 3;
        const int h  = i & 7;
        const int e0 = edge[e];
        att[i] = att[i] / ssum[e0 * H + h];
    }
}

extern "C" void kernel_launch(void* const* d_in, const int* in_sizes, int n_in,
                              void* d_out, int out_size, void* d_ws, size_t ws_size,
                              hipStream_t stream) {
    const float* hi     = (const float*)d_in[0];
    const float* radial = (const float*)d_in[1];
    const float* Qw     = (const float*)d_in[2];
    const float* Qb     = (const float*)d_in[3];
    const float* Qrw    = (const float*)d_in[4];
    const float* Qrb    = (const float*)d_in[5];
    const float* Kw     = (const float*)d_in[6];
    const float* Kb     = (const float*)d_in[7];
    const int*   edge   = (const int*)d_in[8];

    float* att   = (float*)d_out;                    // [E, H]
    float* prods = att + (size_t)EDGES * H;          // [E, H]

    __half* qh  = (__half*)d_ws;                     // N*AD fp16
    __half* kh  = qh + (size_t)N_NODES * AD;         // N*AD fp16
    float*  ssum = (float*)(kh + (size_t)N_NODES * AD); // N*H fp32

    zero_kernel<<<(N_NODES * H + 255) / 256, 256, 0, stream>>>(ssum, N_NODES * H);
    proj_kernel<<<(N_NODES + 31) / 32, 256, 0, stream>>>(hi, Qw, Qb, Kw, Kb, qh, kh);
    edge_kernel<<<(EDGES * H + 255) / 256, 256, 0, stream>>>(qh, kh, radial, edge,
                                                             Qrw, Qrb, att, prods, ssum);
    norm_kernel<<<(EDGES * H + 255) / 256, 256, 0, stream>>>(att, ssum, edge);
}

// Round 3
// 358.377 us; speedup vs baseline: 2.2865x; 1.4742x over previous
//
#include <hip/hip_runtime.h>
#include <hip/hip_fp16.h>
#include <math.h>

#define N_NODES 50000
#define EDGES   1600000
#define IN_F    256
#define AD      128
#define H       8
#define DK      16

typedef __attribute__((ext_vector_type(8))) _Float16 half8;
typedef __attribute__((ext_vector_type(4))) _Float16 half4;
typedef __attribute__((ext_vector_type(4))) float floatx4;

// ---------------- zero init for the segment-sum table ----------------
__global__ void zero_kernel(float* __restrict__ p, int n) {
    int i = blockIdx.x * blockDim.x + threadIdx.x;
    if (i < n) p[i] = 0.0f;
}

// ---------------- weight swizzle: fp32 Qw/Kw -> fragment-ready fp16 ------
// B-operand fragment layout for mfma_f32_16x16x32_f16:
//   B[k][n] with n = lane&15, k = (lane>>4)*8 + j  (j = 0..7 within half8)
// Wfrag[((kb*16 + nb)*64 + lane)] holds the half8 for K-block kb (32 wide),
// col-block nb (16 wide). B[k][n] = Wc[n][k], Wc rows 0..127 = Qw, 128.. = Kw.
__global__ void wswz_kernel(const float* __restrict__ Qw,
                            const float* __restrict__ Kw,
                            half8* __restrict__ Wfrag) {
    const int idx = blockIdx.x * blockDim.x + threadIdx.x;  // 8*16*64 = 8192
    if (idx >= 8 * 16 * 64) return;
    const int lane = idx & 63;
    const int nb   = (idx >> 6) & 15;
    const int kb   = idx >> 10;
    const int n    = nb * 16 + (lane & 15);
    const int k0   = kb * 32 + ((lane >> 4) << 3);
    const float* row = (n < AD) ? (Qw + (size_t)n * IN_F)
                                : (Kw + (size_t)(n - AD) * IN_F);
    half8 v;
#pragma unroll
    for (int j = 0; j < 8; j++) v[j] = (_Float16)row[k0 + j];
    Wfrag[idx] = v;
}

// ---------------- MFMA projection: [64 rows x 256 cols] per block --------
// 4 waves; wave w owns cols [w*64, w*64+64). LDS stages the 64x256 hi tile
// as fp16 (row padded +8 halves -> <=2-way bank aliasing, free). K-loop of
// 8 x mfma_f32_16x16x32_f16, 16 MFMAs/iter. Epilogue adds bias, writes fp16.
#define APAD 264
__global__ __launch_bounds__(256) void proj_mfma_kernel(
    const float* __restrict__ hi, const half8* __restrict__ Wfrag,
    const float* __restrict__ Qb, const float* __restrict__ Kb,
    __half* __restrict__ qh, __half* __restrict__ kh)
{
    __shared__ _Float16 Atile[64][APAD];   // 33.8 KB
    const int r0 = blockIdx.x * 64;
    const int t  = threadIdx.x;

    // cooperative load + fp32->fp16 convert: 4 threads per row, each 16 float4
    {
        const int row = t >> 2;
        const int c4  = t & 3;
        const bool valid = (r0 + row) < N_NODES;
        const float4* src = (const float4*)(hi + (size_t)(r0 + row) * IN_F);
#pragma unroll
        for (int i = 0; i < 16; i++) {
            const int col4 = c4 + i * 4;            // float4 index in row
            float4 v = valid ? src[col4] : make_float4(0.f, 0.f, 0.f, 0.f);
            half4 hv;
            hv[0] = (_Float16)v.x; hv[1] = (_Float16)v.y;
            hv[2] = (_Float16)v.z; hv[3] = (_Float16)v.w;
            *(half4*)&Atile[row][col4 * 4] = hv;
        }
    }
    __syncthreads();

    const int wave = t >> 6;
    const int lane = t & 63;
    const int m    = lane & 15;        // row within 16-block / out-col within 16
    const int quad = lane >> 4;

    floatx4 acc[4][4];                 // [row-block][col-block] 64 VGPRs
#pragma unroll
    for (int a = 0; a < 4; a++)
#pragma unroll
        for (int b = 0; b < 4; b++) acc[a][b] = (floatx4)0.f;

#pragma unroll
    for (int kb = 0; kb < 8; kb++) {
        half8 Af[4], Bf[4];
#pragma unroll
        for (int rb = 0; rb < 4; rb++)
            Af[rb] = *(const half8*)&Atile[rb * 16 + m][kb * 32 + quad * 8];
#pragma unroll
        for (int nbi = 0; nbi < 4; nbi++)
            Bf[nbi] = Wfrag[(size_t)(kb * 16 + wave * 4 + nbi) * 64 + lane];
#pragma unroll
        for (int rb = 0; rb < 4; rb++)
#pragma unroll
            for (int nbi = 0; nbi < 4; nbi++)
                acc[rb][nbi] = __builtin_amdgcn_mfma_f32_16x16x32_f16(
                    Af[rb], Bf[nbi], acc[rb][nbi], 0, 0, 0);
    }

    // epilogue: C/D layout col = lane&15, row = quad*4 + reg
#pragma unroll
    for (int nbi = 0; nbi < 4; nbi++) {
        const int n   = wave * 64 + nbi * 16 + m;       // 0..255 combined col
        const float bias = (n < AD) ? Qb[n] : Kb[n - AD];
        __half* out   = (n < AD) ? qh : kh;
        const int ncol = n & (AD - 1);
#pragma unroll
        for (int rb = 0; rb < 4; rb++) {
#pragma unroll
            for (int reg = 0; reg < 4; reg++) {
                const int row = r0 + rb * 16 + quad * 4 + reg;
                if (row < N_NODES)
                    out[(size_t)row * AD + ncol] = __float2half(acc[rb][nbi][reg] + bias);
            }
        }
    }
}

// ---------------- edge pass: one THREAD per (edge, head) ----------------
__global__ __launch_bounds__(256) void edge_kernel(
    const __half* __restrict__ qh, const __half* __restrict__ kh,
    const float* __restrict__ radial, const int* __restrict__ edge,
    const float* __restrict__ Qrw, const float* __restrict__ Qrb,
    float* __restrict__ att, float* __restrict__ prods, float* __restrict__ ssum)
{
    const int t = blockIdx.x * blockDim.x + threadIdx.x;
    const int e = t >> 3;
    const int h = t & 7;
    if (e >= EDGES) return;

    const int e0 = edge[e];
    const int e1 = edge[EDGES + e];

    const half8* qp = (const half8*)(qh + (size_t)e0 * AD + h * DK);
    const half8* kp = (const half8*)(kh + (size_t)e1 * AD + h * DK);
    half8 q0 = qp[0], q1 = qp[1];
    half8 k0 = kp[0], k1 = kp[1];

    const float4* rw4 = (const float4*)(Qrw + h * DK);
    const float4* rb4 = (const float4*)(Qrb + h * DK);
    float rw[16], rb[16];
#pragma unroll
    for (int j = 0; j < 4; j++) {
        float4 w = rw4[j];
        rw[4 * j + 0] = w.x; rw[4 * j + 1] = w.y; rw[4 * j + 2] = w.z; rw[4 * j + 3] = w.w;
        float4 b = rb4[j];
        rb[4 * j + 0] = b.x; rb[4 * j + 1] = b.y; rb[4 * j + 2] = b.z; rb[4 * j + 3] = b.w;
    }

    float a = 0.f, b = 0.f, c = 0.f;
#pragma unroll
    for (int i = 0; i < 8; i++) {
        float qf = (float)q0[i], kf = (float)k0[i];
        a += qf * kf;
        b += rw[i] * kf;
        c += rb[i] * kf;
    }
#pragma unroll
    for (int i = 0; i < 8; i++) {
        float qf = (float)q1[i], kf = (float)k1[i];
        a += qf * kf;
        b += rw[8 + i] * kf;
        c += rb[8 + i] * kf;
    }

    const float r = radial[e];
    const float p = (a + r * b + c) * 0.25f;   // 1/sqrt(DK) = 0.25
    prods[t] = p;
    const float ex = __expf(p);
    att[t] = ex;
    atomicAdd(&ssum[e0 * H + h], ex);
}

// ---------------- normalize: attention = ex / s[e0,h] ------------------
__global__ __launch_bounds__(256) void norm_kernel(
    float* __restrict__ att, const float* __restrict__ ssum,
    const int* __restrict__ edge)
{
    const int i = blockIdx.x * blockDim.x + threadIdx.x;
    if (i < EDGES * H) {
        const int e  = i >> 3;
        const int h  = i & 7;
        const int e0 = edge[e];
        att[i] = att[i] / ssum[e0 * H + h];
    }
}

extern "C" void kernel_launch(void* const* d_in, const int* in_sizes, int n_in,
                              void* d_out, int out_size, void* d_ws, size_t ws_size,
                              hipStream_t stream) {
    const float* hi     = (const float*)d_in[0];
    const float* radial = (const float*)d_in[1];
    const float* Qw     = (const float*)d_in[2];
    const float* Qb     = (const float*)d_in[3];
    const float* Qrw    = (const float*)d_in[4];
    const float* Qrb    = (const float*)d_in[5];
    const float* Kw     = (const float*)d_in[6];
    const float* Kb     = (const float*)d_in[7];
    const int*   edge   = (const int*)d_in[8];

    float* att   = (float*)d_out;                    // [E, H]
    float* prods = att + (size_t)EDGES * H;          // [E, H]

    __half* qh   = (__half*)d_ws;                    // N*AD fp16
    __half* kh   = qh + (size_t)N_NODES * AD;        // N*AD fp16
    float*  ssum = (float*)(kh + (size_t)N_NODES * AD);   // N*H fp32
    half8*  Wfrag = (half8*)(ssum + (size_t)N_NODES * H); // 8192 * 16 B

    zero_kernel<<<(N_NODES * H + 255) / 256, 256, 0, stream>>>(ssum, N_NODES * H);
    wswz_kernel<<<(8 * 16 * 64 + 255) / 256, 256, 0, stream>>>(Qw, Kw, Wfrag);
    proj_mfma_kernel<<<(N_NODES + 63) / 64, 256, 0, stream>>>(hi, Wfrag, Qb, Kb, qh, kh);
    edge_kernel<<<(EDGES * H + 255) / 256, 256, 0, stream>>>(qh, kh, radial, edge,
                                                             Qrw, Qrb, att, prods, ssum);
    norm_kernel<<<(EDGES * H + 255) / 256, 256, 0, stream>>>(att, ssum, edge);
}